// Round 9
// baseline (217.913 us; speedup 1.0000x reference)
//
#include <hip/hip_runtime.h>
#include <hip/hip_bf16.h>

// Problem: B=4, T=1024, C=1024, H=16, D=64, MAX_LEN=1024, NPOS=2047
// Pipeline:
//   table_reduce rel_pos_emb -> (2047,16)
//   gemm_bt<0,f32A>: qkv = x @ qkv_w^T + b (cvt fused into staging) -> scatter bf16;
//                    Q,K as (B,H,T,D), V as (B,H,D,T)
//   attn_mfma: flash causal, 128-query blocks (8 waves), MFMA QK^T/PV -> y (B,T,C) bf16
//   gemm_bt<1,bf16A>: out = y @ proj_w^T + b (proj_w cvt fused) -> fp32 d_out
//
// gemm_bt R9: 128x128 tile, *BK=64*, 8 waves (512 thr), wave = 64x32 quadrant,
// 16 MFMA per barrier-pair (vs 8 at BK=32) -- halves barrier events, doubles
// bytes in flight per load phase. Prefetch: named scalar regs, dist-1 (R7's
// indexed reg arrays spilled: WRITE_SIZE 24->250 MB. Never again).
// attn R9: dist-1 register prefetch of K/V -- R8 loaded global->LDS between
// the two barriers, exposing full L2 latency on each of 72 tile-steps.
//
// Workspace layout (bytes):
//   table@ 16777216  : 2047x16 f32     (128 KB)
//   qkvb @ 16908288  : (3,4,16,64K) bf16 (24 MB)
//   y    @ 42074112  : 4096x1024 bf16  (8 MB)

typedef __bf16 bf16x8 __attribute__((ext_vector_type(8)));
typedef float f32x4 __attribute__((ext_vector_type(4)));

__device__ __forceinline__ float bf2f(unsigned short u) {
    return __uint_as_float(((unsigned)u) << 16);
}
__device__ __forceinline__ unsigned short f2bf(float f) {
    __hip_bfloat16 h = __float2bfloat16(f);
    return *reinterpret_cast<unsigned short*>(&h);
}
__device__ __forceinline__ int4 cvt8(float4 a, float4 b) {
    union { unsigned short s[8]; int4 v; } u;
    u.s[0] = f2bf(a.x); u.s[1] = f2bf(a.y); u.s[2] = f2bf(a.z); u.s[3] = f2bf(a.w);
    u.s[4] = f2bf(b.x); u.s[5] = f2bf(b.y); u.s[6] = f2bf(b.z); u.s[7] = f2bf(b.w);
    return u.v;
}

// ---------------- rel_pos_emb (2047,1024) -> table (2047,16) ----------------
__global__ __launch_bounds__(256) void table_reduce(const float* __restrict__ rel,
                                                    float* __restrict__ table) {
    const int p = blockIdx.x;
    const int tid = threadIdx.x, lane = tid & 63, wave = tid >> 6;
    const float* r = rel + (size_t)p * 1024;
    float s[4];
#pragma unroll
    for (int k = 0; k < 4; ++k) s[k] = r[tid + 256 * k];
#pragma unroll
    for (int k = 0; k < 4; ++k) {
        float v = s[k];
        for (int o = 32; o; o >>= 1) v += __shfl_xor(v, o, 64);
        if (lane == 0) table[p * 16 + wave + 4 * k] = v;
    }
}

// ---------------- bf16 MFMA GEMM: C = A B^T + bias, BK=64 ----------------
// 512 threads, 8 waves: wr=wave&1 (64-row half), wc=wave>>1 (32-col quarter).
// Staging: thread t -> row t>>2, 16-short chunk (t&3)*16. LDS stride 72
// shorts (144B): b128-aligned, 2-way bank aliasing (free, m136).
// EPI=0: scatter bf16 into qkv planes (Q,K [t][d], V [d][t]). EPI=1: fp32 out.
template <int EPI, bool AF32>
__global__ __launch_bounds__(512) void gemm_bt(const void* __restrict__ Ain,
                                               const float* __restrict__ Bf,
                                               const float* __restrict__ bias,
                                               unsigned short* __restrict__ outb,
                                               float* __restrict__ outf,
                                               int M, int N, int K) {
    __shared__ __attribute__((aligned(16))) unsigned short As[128 * 72];
    __shared__ __attribute__((aligned(16))) unsigned short Bs[128 * 72];
    const int bm = blockIdx.x * 128, bn = blockIdx.y * 128;
    const int tid = threadIdx.x, lane = tid & 63, wave = tid >> 6;
    const int wr = wave & 1, wc = wave >> 1;  // wc in 0..3
    const int quad = lane >> 4, lm = lane & 15;

    const int srow = tid >> 2;         // 0..127
    const int scol = (tid & 3) * 16;   // shorts / elements
    const float* ApF          = (const float*)Ain + (size_t)(bm + srow) * K + scol;
    const unsigned short* ApH = (const unsigned short*)Ain + (size_t)(bm + srow) * K + scol;
    const float* BpF          = Bf + (size_t)(bn + srow) * K + scol;
    unsigned short* AsW = &As[srow * 72 + scol];
    unsigned short* BsW = &Bs[srow * 72 + scol];

    f32x4 acc[4][2];
#pragma unroll
    for (int r = 0; r < 4; ++r)
#pragma unroll
        for (int c = 0; c < 2; ++c) acc[r][c] = (f32x4){0.f, 0.f, 0.f, 0.f};

    // prologue prefetch of tile 0 (named scalars -- no indexed reg arrays!)
    float4 pa0, pa1, pa2, pa3, pb0, pb1, pb2, pb3;
    int4 pah0, pah1;
    if (AF32) {
        pa0 = *(const float4*)(ApF);
        pa1 = *(const float4*)(ApF + 4);
        pa2 = *(const float4*)(ApF + 8);
        pa3 = *(const float4*)(ApF + 12);
    } else {
        pah0 = *(const int4*)(ApH);
        pah1 = *(const int4*)(ApH + 8);
    }
    pb0 = *(const float4*)(BpF);
    pb1 = *(const float4*)(BpF + 4);
    pb2 = *(const float4*)(BpF + 8);
    pb3 = *(const float4*)(BpF + 12);

    for (int kk = 0; kk < K; kk += 64) {
        // drain prefetch into LDS (cvt fused)
        *(int4*)(AsW)     = AF32 ? cvt8(pa0, pa1) : pah0;
        *(int4*)(AsW + 8) = AF32 ? cvt8(pa2, pa3) : pah1;
        *(int4*)(BsW)     = cvt8(pb0, pb1);
        *(int4*)(BsW + 8) = cvt8(pb2, pb3);
        __syncthreads();

        if (kk + 64 < K) {
            if (AF32) {
                pa0 = *(const float4*)(ApF + kk + 64);
                pa1 = *(const float4*)(ApF + kk + 68);
                pa2 = *(const float4*)(ApF + kk + 72);
                pa3 = *(const float4*)(ApF + kk + 76);
            } else {
                pah0 = *(const int4*)(ApH + kk + 64);
                pah1 = *(const int4*)(ApH + kk + 72);
            }
            pb0 = *(const float4*)(BpF + kk + 64);
            pb1 = *(const float4*)(BpF + kk + 68);
            pb2 = *(const float4*)(BpF + kk + 72);
            pb3 = *(const float4*)(BpF + kk + 76);
        }

#pragma unroll
        for (int ks = 0; ks < 2; ++ks) {
            bf16x8 af[4], bfr[2];
#pragma unroll
            for (int r = 0; r < 4; ++r)
                af[r] = *(const bf16x8*)(&As[(64 * wr + 16 * r + lm) * 72 + ks * 32 + quad * 8]);
#pragma unroll
            for (int c = 0; c < 2; ++c)
                bfr[c] = *(const bf16x8*)(&Bs[(32 * wc + 16 * c + lm) * 72 + ks * 32 + quad * 8]);
#pragma unroll
            for (int r = 0; r < 4; ++r)
#pragma unroll
                for (int c = 0; c < 2; ++c)
                    acc[r][c] = __builtin_amdgcn_mfma_f32_16x16x32_bf16(af[r], bfr[c], acc[r][c], 0, 0, 0);
        }
        __syncthreads();
    }

    // C/D layout: col = lane&15, row = (lane>>4)*4 + reg
#pragma unroll
    for (int r = 0; r < 4; ++r)
#pragma unroll
        for (int c = 0; c < 2; ++c)
#pragma unroll
            for (int i = 0; i < 4; ++i) {
                const int row = bm + 64 * wr + 16 * r + quad * 4 + i;
                const int col = bn + 32 * wc + 16 * c + lm;
                const float v = acc[r][c][i] + bias[col];
                if (EPI == 0) {
                    const int b = row >> 10, t = row & 1023;
                    const int s3 = col >> 10, rem = col & 1023;
                    const int h = rem >> 6, d = rem & 63;
                    const size_t base = (((size_t)s3 * 4 + b) * 16 + h) * 65536;
                    const size_t off = base + (s3 == 2 ? (size_t)d * 1024 + t
                                                       : (size_t)t * 64 + d);
                    outb[off] = f2bf(v);
                } else {
                    outf[(size_t)row * N + col] = v;
                }
            }
}

// ---------------- MFMA flash causal attention, 128-query blocks ----------------
// R9: K/V staged via dist-1 register prefetch (load for tile kt+1 issued right
// after the publish barrier, flies across the whole compute phase).
__global__ __launch_bounds__(512) void attn_mfma(const unsigned short* __restrict__ qkvb,
                                                 const float* __restrict__ table,
                                                 unsigned short* __restrict__ y) {
    const int bh = blockIdx.x, b = bh >> 4, h = bh & 15;
    const int qb = (7 - blockIdx.y) * 128;  // longest blocks first
    const int tid = threadIdx.x, lane = tid & 63, wave = tid >> 6;
    const int quad = lane >> 4, lm = lane & 15;

    __shared__ __attribute__((aligned(16))) unsigned short Ks[64][72];      // [j][d]
    __shared__ __attribute__((aligned(16))) unsigned short Vs[64][72];      // [d][j] (V^T)
    __shared__ __attribute__((aligned(16))) unsigned short Ps[8][16][72];   // per-wave P
    __shared__ float tb[1280];

    const unsigned short* Qg  = qkvb + ((size_t)(b)*16 + h) * 65536;       // [t][d]
    const unsigned short* Kg  = qkvb + ((size_t)(4 + b)*16 + h) * 65536;   // [t][d]
    const unsigned short* Vtg = qkvb + ((size_t)(8 + b)*16 + h) * 65536;   // [d][t]

    const bf16x8 qf0 = *(const bf16x8*)(Qg + (size_t)(qb + wave * 16 + lm) * 64 + quad * 8);
    const bf16x8 qf1 = *(const bf16x8*)(Qg + (size_t)(qb + wave * 16 + lm) * 64 + 32 + quad * 8);

    const int tbn = qb + 255;
    for (int i = tid; i < tbn; i += 512) tb[i] = table[(896 + i) * 16 + h];

    f32x4 oacc[4];
#pragma unroll
    for (int nb = 0; nb < 4; ++nb) oacc[nb] = (f32x4){0.f, 0.f, 0.f, 0.f};
    float mi[4], li[4];
#pragma unroll
    for (int i = 0; i < 4; ++i) { mi[i] = -1e30f; li[i] = 0.f; }

    const int r0 = tid >> 3, c0 = (tid & 7) * 8;
    int4 pk = *(const int4*)(Kg + (size_t)r0 * 64 + c0);
    int4 pv = *(const int4*)(Vtg + (size_t)r0 * 1024 + c0);

    const int ktiles = qb / 64 + 2;
    for (int kt = 0; kt < ktiles; ++kt) {
        *(int4*)&Ks[r0][c0] = pk;
        *(int4*)&Vs[r0][c0] = pv;
        __syncthreads();
        if (kt + 1 < ktiles) {
            pk = *(const int4*)(Kg + (size_t)((kt + 1) * 64 + r0) * 64 + c0);
            pv = *(const int4*)(Vtg + (size_t)r0 * 1024 + (kt + 1) * 64 + c0);
        }

        f32x4 s[4];
#pragma unroll
        for (int nb = 0; nb < 4; ++nb) {
            bf16x8 k0 = *(const bf16x8*)(&Ks[nb * 16 + lm][quad * 8]);
            bf16x8 k1 = *(const bf16x8*)(&Ks[nb * 16 + lm][32 + quad * 8]);
            s[nb] = (f32x4){0.f, 0.f, 0.f, 0.f};
            s[nb] = __builtin_amdgcn_mfma_f32_16x16x32_bf16(qf0, k0, s[nb], 0, 0, 0);
            s[nb] = __builtin_amdgcn_mfma_f32_16x16x32_bf16(qf1, k1, s[nb], 0, 0, 0);
        }

        const int qrow0 = qb + wave * 16 + quad * 4;
        const int jbase = kt * 64 + lm;
#pragma unroll
        for (int nb = 0; nb < 4; ++nb)
#pragma unroll
            for (int i = 0; i < 4; ++i) {
                const int q = qrow0 + i, j = jbase + nb * 16;
                const float v = fmaf(s[nb][i], 0.125f, tb[q - j + 127]);
                s[nb][i] = (j <= q) ? v : -1e30f;
            }

        float mnew[4], al[4];
#pragma unroll
        for (int i = 0; i < 4; ++i) {
            float mx = fmaxf(fmaxf(s[0][i], s[1][i]), fmaxf(s[2][i], s[3][i]));
            mx = fmaxf(mx, __shfl_xor(mx, 1, 64));
            mx = fmaxf(mx, __shfl_xor(mx, 2, 64));
            mx = fmaxf(mx, __shfl_xor(mx, 4, 64));
            mx = fmaxf(mx, __shfl_xor(mx, 8, 64));
            mnew[i] = fmaxf(mi[i], mx);
            al[i] = __expf(mi[i] - mnew[i]);
            mi[i] = mnew[i];
        }
#pragma unroll
        for (int nb = 0; nb < 4; ++nb)
#pragma unroll
            for (int i = 0; i < 4; ++i) s[nb][i] = __expf(s[nb][i] - mnew[i]);
#pragma unroll
        for (int i = 0; i < 4; ++i) {
            float sm = (s[0][i] + s[1][i]) + (s[2][i] + s[3][i]);
            sm += __shfl_xor(sm, 1, 64);
            sm += __shfl_xor(sm, 2, 64);
            sm += __shfl_xor(sm, 4, 64);
            sm += __shfl_xor(sm, 8, 64);
            li[i] = li[i] * al[i] + sm;
        }

#pragma unroll
        for (int nb = 0; nb < 4; ++nb)
#pragma unroll
            for (int i = 0; i < 4; ++i)
                Ps[wave][quad * 4 + i][nb * 16 + lm] = f2bf(s[nb][i]);

#pragma unroll
        for (int nb = 0; nb < 4; ++nb)
#pragma unroll
            for (int i = 0; i < 4; ++i) oacc[nb][i] *= al[i];

        const bf16x8 p0 = *(const bf16x8*)(&Ps[wave][lm][quad * 8]);
        const bf16x8 p1 = *(const bf16x8*)(&Ps[wave][lm][32 + quad * 8]);
#pragma unroll
        for (int nb = 0; nb < 4; ++nb) {
            bf16x8 v0 = *(const bf16x8*)(&Vs[nb * 16 + lm][quad * 8]);
            bf16x8 v1 = *(const bf16x8*)(&Vs[nb * 16 + lm][32 + quad * 8]);
            oacc[nb] = __builtin_amdgcn_mfma_f32_16x16x32_bf16(p0, v0, oacc[nb], 0, 0, 0);
            oacc[nb] = __builtin_amdgcn_mfma_f32_16x16x32_bf16(p1, v1, oacc[nb], 0, 0, 0);
        }
        __syncthreads();
    }

    float inv[4];
#pragma unroll
    for (int i = 0; i < 4; ++i) inv[i] = 1.0f / li[i];
#pragma unroll
    for (int nb = 0; nb < 4; ++nb)
#pragma unroll
        for (int i = 0; i < 4; ++i) {
            const int q = qb + wave * 16 + quad * 4 + i;
            const int d = nb * 16 + lm;
            y[((size_t)(b * 1024 + q)) * 1024 + h * 64 + d] = f2bf(oacc[nb][i] * inv[i]);
        }
}

extern "C" void kernel_launch(void* const* d_in, const int* in_sizes, int n_in,
                              void* d_out, int out_size, void* d_ws, size_t ws_size,
                              hipStream_t stream) {
    const float* x      = (const float*)d_in[0];
    const float* qkv_w  = (const float*)d_in[1];
    const float* qkv_b  = (const float*)d_in[2];
    const float* proj_w = (const float*)d_in[3];
    const float* proj_b = (const float*)d_in[4];
    const float* rel    = (const float*)d_in[5];
    float* out = (float*)d_out;

    char* ws = (char*)d_ws;
    float* table         = (float*)(ws + 16777216);
    unsigned short* qkvb = (unsigned short*)(ws + 16908288);
    unsigned short* yb   = (unsigned short*)(ws + 42074112);

    table_reduce<<<2047, 256, 0, stream>>>(rel, table);
    gemm_bt<0, true><<<dim3(32, 24), 512, 0, stream>>>(x, qkv_w, qkv_b, qkvb, nullptr,
                                                       4096, 3072, 1024);
    attn_mfma<<<dim3(64, 8), 512, 0, stream>>>(qkvb, table, yb);
    gemm_bt<1, false><<<dim3(32, 8), 512, 0, stream>>>(yb, proj_w, proj_b, nullptr, out,
                                                       4096, 1024, 1024);
}

// Round 10
// 193.126 us; speedup vs baseline: 1.1284x; 1.1284x over previous
//
#include <hip/hip_runtime.h>
#include <hip/hip_bf16.h>

// Problem: B=4, T=1024, C=1024, H=16, D=64, MAX_LEN=1024, NPOS=2047
// Pipeline:
//   table_reduce rel_pos_emb -> (2047,16)
//   gemm_bt<0,f32A>: qkv = x @ qkv_w^T + b (cvt fused into staging) -> scatter bf16;
//                    Q,K as (B,H,T,D), V as (B,H,D,T)
//   attn_mfma: flash causal, 128-query blocks (8 waves), S^T-softmax -> y (B,T,C) bf16
//   gemm_bt<1,bf16A>: out = y @ proj_w^T + b (proj_w cvt fused) -> fp32 d_out
//
// gemm_bt: EXACT R8 structure (best measured 61us; MfmaUtil 16%, occ 48%).
// R9's BK=64 regressed (m132 failure mode: LDS 20->37KB cut occupancy 48->33%,
// prefetch regs 40->60 VGPR lengthened drain). BK=32 + 8 waves is the plateau.
// R7 lesson: NAMED scalar prefetch regs only (indexed arrays spill to scratch).
//
// attn R10: compute S^T = K Q^T (operand swap; reads unchanged). Each lane
// then owns ONE query (q = lane&15, lane-constant): mi/li scalar, softmax
// reductions 32->4 shfl (cross-quad only), P store 16x ds_write_b16 ->
// 4x ds_write_b64 (4 consecutive j per reg quad). PV A-frag read still b128.
// alpha/inv broadcast back to C-layout rows via 4 bpermutes each.
//
// Workspace layout (bytes):
//   table@ 16777216  : 2047x16 f32     (128 KB)
//   qkvb @ 16908288  : (3,4,16,64K) bf16 (24 MB)
//   y    @ 42074112  : 4096x1024 bf16  (8 MB)

typedef __bf16 bf16x8 __attribute__((ext_vector_type(8)));
typedef float f32x4 __attribute__((ext_vector_type(4)));

__device__ __forceinline__ float bf2f(unsigned short u) {
    return __uint_as_float(((unsigned)u) << 16);
}
__device__ __forceinline__ unsigned short f2bf(float f) {
    __hip_bfloat16 h = __float2bfloat16(f);
    return *reinterpret_cast<unsigned short*>(&h);
}
__device__ __forceinline__ int4 cvt8(float4 a, float4 b) {
    union { unsigned short s[8]; int4 v; } u;
    u.s[0] = f2bf(a.x); u.s[1] = f2bf(a.y); u.s[2] = f2bf(a.z); u.s[3] = f2bf(a.w);
    u.s[4] = f2bf(b.x); u.s[5] = f2bf(b.y); u.s[6] = f2bf(b.z); u.s[7] = f2bf(b.w);
    return u.v;
}

// ---------------- rel_pos_emb (2047,1024) -> table (2047,16) ----------------
__global__ __launch_bounds__(256) void table_reduce(const float* __restrict__ rel,
                                                    float* __restrict__ table) {
    const int p = blockIdx.x;
    const int tid = threadIdx.x, lane = tid & 63, wave = tid >> 6;
    const float* r = rel + (size_t)p * 1024;
    float s[4];
#pragma unroll
    for (int k = 0; k < 4; ++k) s[k] = r[tid + 256 * k];
#pragma unroll
    for (int k = 0; k < 4; ++k) {
        float v = s[k];
        for (int o = 32; o; o >>= 1) v += __shfl_xor(v, o, 64);
        if (lane == 0) table[p * 16 + wave + 4 * k] = v;
    }
}

// ---------------- bf16 MFMA GEMM: C = A B^T + bias (exact R8) ----------------
// 512 threads, 8 waves: wr=wave&1 (64-row half), wc=wave>>1 (32-col quarter).
// Staging: thread t -> row t>>2, 8-short chunk (t&3)*8; A fp32 (AF32) loads
// 2 float4 + cvt, else 1 int4; B always fp32 + cvt.
// EPI=0: scatter bf16 into qkv planes (Q,K [t][d], V [d][t]). EPI=1: fp32 out.
template <int EPI, bool AF32>
__global__ __launch_bounds__(512) void gemm_bt(const void* __restrict__ Ain,
                                               const float* __restrict__ Bf,
                                               const float* __restrict__ bias,
                                               unsigned short* __restrict__ outb,
                                               float* __restrict__ outf,
                                               int M, int N, int K) {
    __shared__ __attribute__((aligned(16))) unsigned short As[128 * 40];
    __shared__ __attribute__((aligned(16))) unsigned short Bs[128 * 40];
    const int bm = blockIdx.x * 128, bn = blockIdx.y * 128;
    const int tid = threadIdx.x, lane = tid & 63, wave = tid >> 6;
    const int wr = wave & 1, wc = wave >> 1;  // wc in 0..3
    const int quad = lane >> 4, lm = lane & 15;

    const int srow = tid >> 2;        // 0..127
    const int scol = (tid & 3) * 8;   // shorts / elements
    const float* ApF          = (const float*)Ain + (size_t)(bm + srow) * K + scol;
    const unsigned short* ApH = (const unsigned short*)Ain + (size_t)(bm + srow) * K + scol;
    const float* BpF          = Bf + (size_t)(bn + srow) * K + scol;
    unsigned short* AsW = &As[srow * 40 + scol];
    unsigned short* BsW = &Bs[srow * 40 + scol];

    f32x4 acc[4][2];
#pragma unroll
    for (int r = 0; r < 4; ++r)
#pragma unroll
        for (int c = 0; c < 2; ++c) acc[r][c] = (f32x4){0.f, 0.f, 0.f, 0.f};

    // prologue prefetch of tile 0 (named scalars -- no indexed reg arrays!)
    float4 paf0, paf1, pbf0, pbf1;
    int4 pah;
    if (AF32) {
        paf0 = *(const float4*)(ApF);
        paf1 = *(const float4*)(ApF + 4);
    } else {
        pah = *(const int4*)(ApH);
    }
    pbf0 = *(const float4*)(BpF);
    pbf1 = *(const float4*)(BpF + 4);

    for (int kk = 0; kk < K; kk += 32) {
        // drain prefetch into LDS (cvt fused)
        *(int4*)(AsW) = AF32 ? cvt8(paf0, paf1) : pah;
        *(int4*)(BsW) = cvt8(pbf0, pbf1);
        __syncthreads();

        if (kk + 32 < K) {
            if (AF32) {
                paf0 = *(const float4*)(ApF + kk + 32);
                paf1 = *(const float4*)(ApF + kk + 36);
            } else {
                pah = *(const int4*)(ApH + kk + 32);
            }
            pbf0 = *(const float4*)(BpF + kk + 32);
            pbf1 = *(const float4*)(BpF + kk + 36);
        }

        bf16x8 af[4], bfr[2];
#pragma unroll
        for (int r = 0; r < 4; ++r)
            af[r] = *(const bf16x8*)(&As[(64 * wr + 16 * r + lm) * 40 + quad * 8]);
#pragma unroll
        for (int c = 0; c < 2; ++c)
            bfr[c] = *(const bf16x8*)(&Bs[(32 * wc + 16 * c + lm) * 40 + quad * 8]);
#pragma unroll
        for (int r = 0; r < 4; ++r)
#pragma unroll
            for (int c = 0; c < 2; ++c)
                acc[r][c] = __builtin_amdgcn_mfma_f32_16x16x32_bf16(af[r], bfr[c], acc[r][c], 0, 0, 0);
        __syncthreads();
    }

    // C/D layout: col = lane&15, row = (lane>>4)*4 + reg
#pragma unroll
    for (int r = 0; r < 4; ++r)
#pragma unroll
        for (int c = 0; c < 2; ++c)
#pragma unroll
            for (int i = 0; i < 4; ++i) {
                const int row = bm + 64 * wr + 16 * r + quad * 4 + i;
                const int col = bn + 32 * wc + 16 * c + lm;
                const float v = acc[r][c][i] + bias[col];
                if (EPI == 0) {
                    const int b = row >> 10, t = row & 1023;
                    const int s3 = col >> 10, rem = col & 1023;
                    const int h = rem >> 6, d = rem & 63;
                    const size_t base = (((size_t)s3 * 4 + b) * 16 + h) * 65536;
                    const size_t off = base + (s3 == 2 ? (size_t)d * 1024 + t
                                                       : (size_t)t * 64 + d);
                    outb[off] = f2bf(v);
                } else {
                    outf[(size_t)row * N + col] = v;
                }
            }
}

// ---------------- MFMA flash causal attention, S^T-softmax ----------------
// grid (B*H, T/128), block 512 = 8 waves. Wave w owns queries qb+16w..+15.
// S^T = K Q^T: s[nb][i] = S^T[j = kt*64+nb*16+quad*4+i][q = qb+w*16+lm].
// Per lane: ONE query (q const), 16 j-values -> scalar mi/li, 2-shfl
// reductions. P stored [q][j] (4x ds_write_b64), PV reads A=P b128, B=V^T
// b128. O comes out in the standard C-layout (row=q, col=d).
__global__ __launch_bounds__(512) void attn_mfma(const unsigned short* __restrict__ qkvb,
                                                 const float* __restrict__ table,
                                                 unsigned short* __restrict__ y) {
    const int bh = blockIdx.x, b = bh >> 4, h = bh & 15;
    const int qb = (7 - blockIdx.y) * 128;  // longest blocks first
    const int tid = threadIdx.x, lane = tid & 63, wave = tid >> 6;
    const int quad = lane >> 4, lm = lane & 15;

    __shared__ __attribute__((aligned(16))) unsigned short Ks[64][72];      // [j][d]
    __shared__ __attribute__((aligned(16))) unsigned short Vs[64][72];      // [d][j] (V^T)
    __shared__ __attribute__((aligned(16))) unsigned short Ps[8][16][72];   // [wave][q][j]
    __shared__ float tb[1280];

    const unsigned short* Qg  = qkvb + ((size_t)(b)*16 + h) * 65536;       // [t][d]
    const unsigned short* Kg  = qkvb + ((size_t)(4 + b)*16 + h) * 65536;   // [t][d]
    const unsigned short* Vtg = qkvb + ((size_t)(8 + b)*16 + h) * 65536;   // [d][t]

    // Q fragment (serves as MFMA B-operand now; same register layout)
    const bf16x8 qf0 = *(const bf16x8*)(Qg + (size_t)(qb + wave * 16 + lm) * 64 + quad * 8);
    const bf16x8 qf1 = *(const bf16x8*)(Qg + (size_t)(qb + wave * 16 + lm) * 64 + 32 + quad * 8);

    const int tbn = qb + 255;
    for (int i = tid; i < tbn; i += 512) tb[i] = table[(896 + i) * 16 + h];

    f32x4 oacc[4];
#pragma unroll
    for (int nb = 0; nb < 4; ++nb) oacc[nb] = (f32x4){0.f, 0.f, 0.f, 0.f};
    float mi = -1e30f, li = 0.f;  // per-lane: one query q = qb + wave*16 + lm

    const int r0 = tid >> 3, c0 = (tid & 7) * 8;
    int4 pk = *(const int4*)(Kg + (size_t)r0 * 64 + c0);
    int4 pv = *(const int4*)(Vtg + (size_t)r0 * 1024 + c0);

    const int q = qb + wave * 16 + lm;
    const int ktiles = qb / 64 + 2;
    for (int kt = 0; kt < ktiles; ++kt) {
        *(int4*)&Ks[r0][c0] = pk;
        *(int4*)&Vs[r0][c0] = pv;
        __syncthreads();
        if (kt + 1 < ktiles) {
            pk = *(const int4*)(Kg + (size_t)((kt + 1) * 64 + r0) * 64 + c0);
            pv = *(const int4*)(Vtg + (size_t)r0 * 1024 + (kt + 1) * 64 + c0);
        }

        // S^T = K Q^T : A = K rows (j), B = Q rows (q)
        f32x4 s[4];
#pragma unroll
        for (int nb = 0; nb < 4; ++nb) {
            bf16x8 k0 = *(const bf16x8*)(&Ks[nb * 16 + lm][quad * 8]);
            bf16x8 k1 = *(const bf16x8*)(&Ks[nb * 16 + lm][32 + quad * 8]);
            s[nb] = (f32x4){0.f, 0.f, 0.f, 0.f};
            s[nb] = __builtin_amdgcn_mfma_f32_16x16x32_bf16(k0, qf0, s[nb], 0, 0, 0);
            s[nb] = __builtin_amdgcn_mfma_f32_16x16x32_bf16(k1, qf1, s[nb], 0, 0, 0);
        }

        // scale + rel-pos bias + causal mask (q lane-constant)
        const int jb0 = kt * 64 + quad * 4;
#pragma unroll
        for (int nb = 0; nb < 4; ++nb)
#pragma unroll
            for (int i = 0; i < 4; ++i) {
                const int j = jb0 + nb * 16 + i;
                const float v = fmaf(s[nb][i], 0.125f, tb[q - j + 127]);
                s[nb][i] = (j <= q) ? v : -1e30f;
            }

        // online softmax: local 16-reg tree + cross-quad shuffles (xor 16,32)
        float mx = -1e30f;
#pragma unroll
        for (int nb = 0; nb < 4; ++nb)
#pragma unroll
            for (int i = 0; i < 4; ++i) mx = fmaxf(mx, s[nb][i]);
        mx = fmaxf(mx, __shfl_xor(mx, 16, 64));
        mx = fmaxf(mx, __shfl_xor(mx, 32, 64));
        const float mnew = fmaxf(mi, mx);
        const float alpha = __expf(mi - mnew);
        mi = mnew;
#pragma unroll
        for (int nb = 0; nb < 4; ++nb)
#pragma unroll
            for (int i = 0; i < 4; ++i) s[nb][i] = __expf(s[nb][i] - mnew);
        float ps = 0.f;
#pragma unroll
        for (int nb = 0; nb < 4; ++nb)
            ps += (s[nb][0] + s[nb][1]) + (s[nb][2] + s[nb][3]);
        ps += __shfl_xor(ps, 16, 64);
        ps += __shfl_xor(ps, 32, 64);
        li = li * alpha + ps;

        // P store: [wave][q=lm][j], 4 consecutive j per (nb,quad) -> b64
#pragma unroll
        for (int nb = 0; nb < 4; ++nb) {
            union { unsigned short u[4]; int2 v; } p4;
            p4.u[0] = f2bf(s[nb][0]);
            p4.u[1] = f2bf(s[nb][1]);
            p4.u[2] = f2bf(s[nb][2]);
            p4.u[3] = f2bf(s[nb][3]);
            *(int2*)(&Ps[wave][lm][nb * 16 + quad * 4]) = p4.v;
        }

        // broadcast alpha (at lane q=lm) to C-layout rows (q=quad*4+i)
        float alr[4];
#pragma unroll
        for (int i = 0; i < 4; ++i) alr[i] = __shfl(alpha, quad * 4 + i, 64);
#pragma unroll
        for (int nb = 0; nb < 4; ++nb)
#pragma unroll
            for (int i = 0; i < 4; ++i) oacc[nb][i] *= alr[i];

        // O += P V : A = P [q][j] (b128), B = V^T [d][j] (b128)
        const bf16x8 p0 = *(const bf16x8*)(&Ps[wave][lm][quad * 8]);
        const bf16x8 p1 = *(const bf16x8*)(&Ps[wave][lm][32 + quad * 8]);
#pragma unroll
        for (int nb = 0; nb < 4; ++nb) {
            bf16x8 v0 = *(const bf16x8*)(&Vs[nb * 16 + lm][quad * 8]);
            bf16x8 v1 = *(const bf16x8*)(&Vs[nb * 16 + lm][32 + quad * 8]);
            oacc[nb] = __builtin_amdgcn_mfma_f32_16x16x32_bf16(p0, v0, oacc[nb], 0, 0, 0);
            oacc[nb] = __builtin_amdgcn_mfma_f32_16x16x32_bf16(p1, v1, oacc[nb], 0, 0, 0);
        }
        __syncthreads();
    }

    // epilogue: O / li -> y (B,T,C) bf16 (oacc row = q local quad*4+i, col = d)
    const float linv = 1.0f / li;
    float invr[4];
#pragma unroll
    for (int i = 0; i < 4; ++i) invr[i] = __shfl(linv, quad * 4 + i, 64);
#pragma unroll
    for (int nb = 0; nb < 4; ++nb)
#pragma unroll
        for (int i = 0; i < 4; ++i) {
            const int qq = qb + wave * 16 + quad * 4 + i;
            const int d = nb * 16 + lm;
            y[((size_t)(b * 1024 + qq)) * 1024 + h * 64 + d] = f2bf(oacc[nb][i] * invr[i]);
        }
}

extern "C" void kernel_launch(void* const* d_in, const int* in_sizes, int n_in,
                              void* d_out, int out_size, void* d_ws, size_t ws_size,
                              hipStream_t stream) {
    const float* x      = (const float*)d_in[0];
    const float* qkv_w  = (const float*)d_in[1];
    const float* qkv_b  = (const float*)d_in[2];
    const float* proj_w = (const float*)d_in[3];
    const float* proj_b = (const float*)d_in[4];
    const float* rel    = (const float*)d_in[5];
    float* out = (float*)d_out;

    char* ws = (char*)d_ws;
    float* table         = (float*)(ws + 16777216);
    unsigned short* qkvb = (unsigned short*)(ws + 16908288);
    unsigned short* yb   = (unsigned short*)(ws + 42074112);

    table_reduce<<<2047, 256, 0, stream>>>(rel, table);
    gemm_bt<0, true><<<dim3(32, 24), 512, 0, stream>>>(x, qkv_w, qkv_b, qkvb, nullptr,
                                                       4096, 3072, 1024);
    attn_mfma<<<dim3(64, 8), 512, 0, stream>>>(qkvb, table, yb);
    gemm_bt<1, false><<<dim3(32, 8), 512, 0, stream>>>(yb, proj_w, proj_b, nullptr, out,
                                                       4096, 1024, 1024);
}